// Round 1
// baseline (511.688 us; speedup 1.0000x reference)
//
#include <hip/hip_runtime.h>

#define SEQ_LEN 2048
#define BATCH   512
#define HIDDEN  25

__device__ __forceinline__ float fast_rcp(float v) { return __builtin_amdgcn_rcpf(v); }

// One wave (64 threads) per batch element. Lane l (0..49) owns gate rows l and l+50:
//   lanes 0..24:  rows j      (i-gate) and 50+j (g-gate)
//   lanes 25..49: rows 25+j   (f-gate) and 75+j (o-gate)   -> these lanes also own c[j], h[j]
// h is exchanged via a double-buffered 25-float LDS line (in-wave LDS ops are in-order).
__global__ __launch_bounds__(64) void lstm_kernel(
    const float* __restrict__ x,
    const float* __restrict__ W_ih,
    const float* __restrict__ W_hh,
    const float* __restrict__ b_ih,
    const float* __restrict__ b_hh,
    const float* __restrict__ W_lin,
    const float* __restrict__ b_lin,
    float* __restrict__ out)
{
    const int lane = threadIdx.x;
    const int b    = blockIdx.x;

    __shared__ __align__(16) float hbuf[2][32];
    __shared__ float pp[64][29];   // per-step output partials; stride 29 (coprime w/ 32 banks)

    const bool hval = (lane >= HIDDEN && lane < 2 * HIDDEN);   // lanes 25..49
    const int  j    = lane - HIDDEN;

    int r1 = (lane < 2 * HIDDEN) ? lane : 0;   // clamp idle lanes 50..63 to harmless rows
    int r2 = r1 + 2 * HIDDEN;

    float Wr1[HIDDEN], Wr2[HIDDEN];
    #pragma unroll
    for (int k = 0; k < HIDDEN; ++k) {
        Wr1[k] = W_hh[r1 * HIDDEN + k];
        Wr2[k] = W_hh[r2 * HIDDEN + k];
    }
    const float bias1 = b_ih[r1] + b_hh[r1];
    const float bias2 = b_ih[r2] + b_hh[r2];
    const float wi1   = W_ih[r1];
    const float wi2   = W_ih[r2];
    const float wlin  = hval ? W_lin[j] : 0.0f;
    const float blin  = b_lin[0];

    const float LOG2E = 1.4426950408889634f;
    // act2 is tanh on lanes <25 (g-gate), sigmoid on lanes 25..49 (o-gate): tanh(x)=2*sigmoid(2x)-1
    const float k2 = (lane < HIDDEN) ? -2.0f * LOG2E : -LOG2E;
    const float m2 = (lane < HIDDEN) ? 2.0f : 1.0f;
    const float d2 = (lane < HIDDEN) ? -1.0f : 0.0f;

    const int hcol = hval ? j : 31;            // invalid lanes dump into unused col
    const int pcol = hval ? j : 26;
    const int src  = (lane >= HIDDEN) ? (lane - HIDDEN) : 0;   // i*g producer lane

    if (lane < 32) { hbuf[0][lane] = 0.0f; hbuf[1][lane] = 0.0f; }
    __syncthreads();

    float c = 0.0f;
    const float* xb = x + b;
    float xv = xb[(size_t)lane * BATCH];       // x[t=lane][b], staggered prefetch

    auto step = [&](int tt, int rb, int wb) {
        float xt = __uint_as_float(__builtin_amdgcn_readlane(__float_as_uint(xv), tt));

        float hl[HIDDEN];
        {
            const float4* hv = reinterpret_cast<const float4*>(&hbuf[rb][0]);
            float4 q0 = hv[0], q1 = hv[1], q2 = hv[2], q3 = hv[3], q4 = hv[4], q5 = hv[5];
            hl[0]=q0.x;  hl[1]=q0.y;  hl[2]=q0.z;  hl[3]=q0.w;
            hl[4]=q1.x;  hl[5]=q1.y;  hl[6]=q1.z;  hl[7]=q1.w;
            hl[8]=q2.x;  hl[9]=q2.y;  hl[10]=q2.z; hl[11]=q2.w;
            hl[12]=q3.x; hl[13]=q3.y; hl[14]=q3.z; hl[15]=q3.w;
            hl[16]=q4.x; hl[17]=q4.y; hl[18]=q4.z; hl[19]=q4.w;
            hl[20]=q5.x; hl[21]=q5.y; hl[22]=q5.z; hl[23]=q5.w;
            hl[24]=hbuf[rb][24];
        }

        float a1 = fmaf(xt, wi1, bias1);
        float a2 = fmaf(xt, wi2, bias2);
        float a1b = 0.0f, a2b = 0.0f;
        #pragma unroll
        for (int k = 0; k < 24; k += 2) {       // 4 independent FMA chains (~12 deep)
            a1  = fmaf(hl[k],     Wr1[k],     a1);
            a1b = fmaf(hl[k + 1], Wr1[k + 1], a1b);
            a2  = fmaf(hl[k],     Wr2[k],     a2);
            a2b = fmaf(hl[k + 1], Wr2[k + 1], a2b);
        }
        a1 = fmaf(hl[24], Wr1[24], a1) + a1b;
        a2 = fmaf(hl[24], Wr2[24], a2) + a2b;

        float s1   = fast_rcp(1.0f + exp2f(-LOG2E * a1));    // sigmoid (i or f)
        float s2   = fast_rcp(1.0f + exp2f(k2 * a2));
        float act2 = fmaf(s2, m2, d2);                       // tanh(g) or sigmoid(o)
        float prod = s1 * act2;                              // i*g on lanes 0..24
        float ig   = __shfl(prod, src);
        c = fmaf(s1, c, ig);                                 // c = f*c + i*g  (lanes 25..49)
        float th = fmaf(fast_rcp(1.0f + exp2f(-2.0f * LOG2E * c)), 2.0f, -1.0f); // tanh(c)
        float hn = act2 * th;                                // h = o * tanh(c)
        hbuf[wb][hcol] = hn;
        pp[tt][pcol]   = hn * wlin;                          // deferred output partial
    };

    #pragma unroll 1
    for (int tb = 0; tb < SEQ_LEN; tb += 64) {
        float xv_next = 0.0f;
        if (tb + 64 < SEQ_LEN) xv_next = xb[(size_t)(tb + 64 + lane) * BATCH];

        #pragma unroll 1
        for (int tt = 0; tt < 64; tt += 2) {    // parity of global t == parity of tt
            step(tt,     0, 1);
            step(tt + 1, 1, 0);
        }
        __syncthreads();

        // batch-reduce 64 timesteps of output partials; one coalesced-ish store per lane
        float s = blin;
        #pragma unroll
        for (int k = 0; k < HIDDEN; ++k) s += pp[lane][k];
        out[(size_t)(tb + lane) * BATCH + b] = s;
        __syncthreads();

        xv = xv_next;
    }
}

extern "C" void kernel_launch(void* const* d_in, const int* in_sizes, int n_in,
                              void* d_out, int out_size, void* d_ws, size_t ws_size,
                              hipStream_t stream) {
    const float* x     = (const float*)d_in[0];
    const float* W_ih  = (const float*)d_in[1];
    const float* W_hh  = (const float*)d_in[2];
    const float* b_ih  = (const float*)d_in[3];
    const float* b_hh  = (const float*)d_in[4];
    const float* W_lin = (const float*)d_in[5];
    const float* b_lin = (const float*)d_in[6];
    float* outp = (float*)d_out;

    hipLaunchKernelGGL(lstm_kernel, dim3(BATCH), dim3(64), 0, stream,
                       x, W_ih, W_hh, b_ih, b_hh, W_lin, b_lin, outp);
}

// Round 2
// 417.891 us; speedup vs baseline: 1.2245x; 1.2245x over previous
//
#include <hip/hip_runtime.h>

#define SEQ_LEN 2048
#define BATCH   512
#define HIDDEN  25

typedef int v2i __attribute__((ext_vector_type(2)));

__device__ __forceinline__ float fast_rcp(float v)  { return __builtin_amdgcn_rcpf(v); }
__device__ __forceinline__ float fast_exp2(float v) { return __builtin_amdgcn_exp2f(v); }

// Full lane<->lane^32 exchange. permlane32_swap returns (vdst_new, vsrc_new);
// with both inputs = v, one result equals v and the other equals v[lane^32] on
// every lane (whichever polarity the HW uses), so rx+ry-v is polarity-proof.
__device__ __forceinline__ float xswap32(float v) {
#if __has_builtin(__builtin_amdgcn_permlane32_swap)
    v2i r = __builtin_amdgcn_permlane32_swap(__float_as_int(v), __float_as_int(v), false, false);
    return (__int_as_float(r.x) + __int_as_float(r.y)) - v;
#else
    return __shfl_xor(v, 32);
#endif
}

// One wave per batch element. Gate rows re-paired across wave halves:
//   lane j      (0..24):  rows j      (i, sigmoid) and 25+j (f, sigmoid); owns c_j
//   lane 32+j   (0..24):  rows 50+j   (g, tanh)    and 75+j (o, sigmoid); owns h_j
// h is broadcast to all lanes via 25 v_readlane -> SGPRs (no LDS on the
// critical path); the two gate crossings (i*g, tanh(c)->o) are permlane32_swap.
__global__ __launch_bounds__(64) void lstm_kernel(
    const float* __restrict__ x,
    const float* __restrict__ W_ih,
    const float* __restrict__ W_hh,
    const float* __restrict__ b_ih,
    const float* __restrict__ b_hh,
    const float* __restrict__ W_lin,
    const float* __restrict__ b_lin,
    float* __restrict__ out)
{
    const int lane = threadIdx.x;
    const int b    = blockIdx.x;

    __shared__ float pp[64][29];   // deferred output partials; 29 coprime w/ 32 banks

    const bool U  = (lane >= 32);
    const int  j  = lane & 31;
    const int  jj = (j < HIDDEN) ? j : 0;          // clamp idle lanes to a harmless row
    const bool hv = (j < HIDDEN);                  // lane owns a real row pair

    const int r1 = U ? (2 * HIDDEN + jj) : jj;     // i (L) / g (U)
    const int r2 = r1 + HIDDEN;                    // f (L) / o (U)

    float Wr1[HIDDEN], Wr2[HIDDEN];
    #pragma unroll
    for (int k = 0; k < HIDDEN; ++k) {
        Wr1[k] = W_hh[r1 * HIDDEN + k];
        Wr2[k] = W_hh[r2 * HIDDEN + k];
    }
    const float bias1 = b_ih[r1] + b_hh[r1];
    const float bias2 = b_ih[r2] + b_hh[r2];
    const float wi1   = W_ih[r1];
    const float wi2   = W_ih[r2];
    const float wlin  = (U && hv) ? W_lin[jj] : 0.0f;
    const float blin  = b_lin[0];
    const int   pcol  = (U && hv) ? jj : 26;       // inactive lanes dump into unused col

    const float LOG2E = 1.4426950408889634f;
    // act1: sigmoid on L (i), tanh on U (g);  tanh(x) = 2*sigmoid(2x)-1
    const float k1 = U ? (-2.0f * LOG2E) : (-LOG2E);
    const float m1 = U ? 2.0f : 1.0f;
    const float d1 = U ? -1.0f : 0.0f;

    float c  = 0.0f;   // real on L lanes
    float vh = 0.0f;   // real on U lanes (h_j)

    const float* xb = x + b;
    float xv = xb[(size_t)lane * BATCH];           // x[t=lane][b], staggered prefetch

    #pragma unroll 1
    for (int tb = 0; tb < SEQ_LEN; tb += 64) {
        float xv_next = 0.0f;
        if (tb + 64 < SEQ_LEN) xv_next = xb[(size_t)(tb + 64 + lane) * BATCH];

        #pragma unroll 4
        for (int tt = 0; tt < 64; ++tt) {
            // broadcast h(t-1) from U lanes into wave-uniform SGPRs
            float hs[HIDDEN];
            #pragma unroll
            for (int k = 0; k < HIDDEN; ++k)
                hs[k] = __int_as_float(__builtin_amdgcn_readlane(__float_as_int(vh), 32 + k));

            const float xt = __int_as_float(__builtin_amdgcn_readlane(__float_as_int(xv), tt));

            float a1 = fmaf(xt, wi1, bias1);
            float a2 = fmaf(xt, wi2, bias2);
            float b1 = 0.0f, b2 = 0.0f;
            #pragma unroll
            for (int k = 0; k < 24; k += 2) {      // 4 independent FMA chains
                a1 = fmaf(hs[k],     Wr1[k],     a1);
                b1 = fmaf(hs[k + 1], Wr1[k + 1], b1);
                a2 = fmaf(hs[k],     Wr2[k],     a2);
                b2 = fmaf(hs[k + 1], Wr2[k + 1], b2);
            }
            a1 = fmaf(hs[24], Wr1[24], a1) + b1;
            a2 = fmaf(hs[24], Wr2[24], a2) + b2;

            const float A = fmaf(fast_rcp(1.0f + fast_exp2(k1 * a1)), m1, d1); // sig(i) | tanh(g)
            const float B = fast_rcp(1.0f + fast_exp2(-LOG2E * a2));           // sig(f) | sig(o)

            const float ig = A * xswap32(A);       // i*g on both halves
            c = fmaf(B, c, ig);                    // c = f*c + i*g   (valid on L)
            const float th = fmaf(fast_rcp(1.0f + fast_exp2(-2.0f * LOG2E * c)), 2.0f, -1.0f);
            vh = B * xswap32(th);                  // h = o * tanh(c) (valid on U)

            pp[tt][pcol] = vh * wlin;              // deferred output partial
        }
        __syncthreads();

        // reduce 64 timesteps of output partials; one store per lane
        float s = blin;
        #pragma unroll
        for (int k = 0; k < HIDDEN; ++k) s += pp[lane][k];
        out[(size_t)(tb + lane) * BATCH + b] = s;
        __syncthreads();

        xv = xv_next;
    }
}

extern "C" void kernel_launch(void* const* d_in, const int* in_sizes, int n_in,
                              void* d_out, int out_size, void* d_ws, size_t ws_size,
                              hipStream_t stream) {
    const float* x     = (const float*)d_in[0];
    const float* W_ih  = (const float*)d_in[1];
    const float* W_hh  = (const float*)d_in[2];
    const float* b_ih  = (const float*)d_in[3];
    const float* b_hh  = (const float*)d_in[4];
    const float* W_lin = (const float*)d_in[5];
    const float* b_lin = (const float*)d_in[6];
    float* outp = (float*)d_out;

    hipLaunchKernelGGL(lstm_kernel, dim3(BATCH), dim3(64), 0, stream,
                       x, W_ih, W_hh, b_ih, b_hh, W_lin, b_lin, outp);
}

// Round 3
// 362.036 us; speedup vs baseline: 1.4134x; 1.1543x over previous
//
#include <hip/hip_runtime.h>

#define SEQ_LEN 2048
#define BATCH   512
#define HIDDEN  25

typedef int v2i __attribute__((ext_vector_type(2)));

__device__ __forceinline__ float fast_rcp(float v)  { return __builtin_amdgcn_rcpf(v); }
__device__ __forceinline__ float fast_exp2(float v) { return __builtin_amdgcn_exp2f(v); }

// Full lane<->lane^32 exchange, polarity-proof (one of r.x/r.y is always the
// unswapped value, so rx+ry-v == v[lane^32] regardless of HW polarity).
__device__ __forceinline__ float xswap32(float v) {
#if __has_builtin(__builtin_amdgcn_permlane32_swap)
    v2i r = __builtin_amdgcn_permlane32_swap(__float_as_int(v), __float_as_int(v), false, false);
    return (__int_as_float(r.x) + __int_as_float(r.y)) - v;
#else
    return __shfl_xor(v, 32);
#endif
}

// One wave per batch element.
//   L lane j  (0..24):  rows j      (i, sigmoid) and 50+j (g, tanh)  -> i*g local
//   U lane 32+j (0..24): rows 25+j  (f, sigmoid) and 75+j (o, sigmoid); owns c_j, h_j
// Single cross-lane move per step: i*g from L to U (permlane32_swap).
// Activation scales folded into weights: a1,a2 arrive pre-scaled by -log2e
// (sigmoid rows) / -2log2e (g row); cell state kept as c' = -2log2e * c.
__global__ __launch_bounds__(64, 1) void lstm_kernel(
    const float* __restrict__ x,
    const float* __restrict__ W_ih,
    const float* __restrict__ W_hh,
    const float* __restrict__ b_ih,
    const float* __restrict__ b_hh,
    const float* __restrict__ W_lin,
    const float* __restrict__ b_lin,
    float* __restrict__ out)
{
    const int lane = threadIdx.x;
    const int b    = blockIdx.x;

    __shared__ float pp[64][29];   // deferred output partials; 29 coprime w/ 32 banks

    const bool U  = (lane >= 32);
    const int  j  = lane & 31;
    const int  jj = (j < HIDDEN) ? j : 0;          // clamp idle lanes to a harmless row
    const bool hv = (j < HIDDEN);

    const int r1 = U ? (HIDDEN + jj) : jj;                     // f : i  (sigmoid)
    const int r2 = U ? (3 * HIDDEN + jj) : (2 * HIDDEN + jj);  // o : g

    const float LOG2E = 1.4426950408889634f;
    const float s1 = -LOG2E;                       // sigmoid pre-scale
    const float s2 = U ? -LOG2E : (-2.0f * LOG2E); // o: sigmoid, g: tanh(=sig(2x) form)

    float Wr1[HIDDEN], Wr2[HIDDEN];
    #pragma unroll
    for (int k = 0; k < HIDDEN; ++k) {
        Wr1[k] = W_hh[r1 * HIDDEN + k] * s1;
        Wr2[k] = W_hh[r2 * HIDDEN + k] * s2;
    }
    const float bias1 = (b_ih[r1] + b_hh[r1]) * s1;
    const float bias2 = (b_ih[r2] + b_hh[r2]) * s2;
    const float wi1   = W_ih[r1] * s1;
    const float wi2   = W_ih[r2] * s2;
    const float wlin  = (U && hv) ? W_lin[jj] : 0.0f;
    const float blin  = b_lin[0];
    const int   pcol  = (U && hv) ? jj : 26;       // inactive lanes dump into unused col

    float cs = 0.0f;   // c' = -2log2e * c   (real on U lanes)
    float vh = 0.0f;   // h                  (real on U lanes)

    const float* xb = x + b;
    float xv = xb[(size_t)lane * BATCH];           // x[t=lane][b], staggered prefetch

    #pragma unroll 1
    for (int tb = 0; tb < SEQ_LEN; tb += 64) {
        float xv_next = 0.0f;
        if (tb + 64 < SEQ_LEN) xv_next = xb[(size_t)(tb + 64 + lane) * BATCH];

        #pragma unroll 4
        for (int tt = 0; tt < 64; ++tt) {
            // broadcast h(t-1) from U lanes into wave-uniform SGPRs
            float hs[HIDDEN];
            #pragma unroll
            for (int k = 0; k < HIDDEN; ++k)
                hs[k] = __int_as_float(__builtin_amdgcn_readlane(__float_as_int(vh), 32 + k));

            const float xt = __int_as_float(__builtin_amdgcn_readlane(__float_as_int(xv), tt));

            float a1 = fmaf(xt, wi1, bias1);
            float a2 = fmaf(xt, wi2, bias2);
            float b1 = 0.0f, b2 = 0.0f;
            #pragma unroll
            for (int k = 0; k < 24; k += 2) {      // 4 independent FMA chains
                a1 = fmaf(hs[k],     Wr1[k],     a1);
                b1 = fmaf(hs[k + 1], Wr1[k + 1], b1);
                a2 = fmaf(hs[k],     Wr2[k],     a2);
                b2 = fmaf(hs[k + 1], Wr2[k + 1], b2);
            }
            a1 = fmaf(hs[24], Wr1[24], a1) + b1;
            a2 = fmaf(hs[24], Wr2[24], a2) + b2;

            const float R1 = fast_rcp(1.0f + fast_exp2(a1));   // i (L) / f (U)
            const float R2 = fast_rcp(1.0f + fast_exp2(a2));   // sig(2zg) (L) / o (U)

            // L: igs = i * g * (-2log2e), where g = 2*R2 - 1
            const float Gp  = fmaf(R2, -4.0f * LOG2E, 2.0f * LOG2E);
            const float igs = R1 * Gp;
            const float igx = xswap32(igs);        // U lanes receive L's igs

            cs = fmaf(R1, cs, igx);                // c' = f*c' + (-2log2e)*i*g  (U)
            const float R3 = fast_rcp(1.0f + fast_exp2(cs));   // sig(2c) -> tanh(c)=2R3-1
            const float o2 = R2 + R2;              // 2o (off critical path)
            vh = fmaf(o2, R3, -R2);                // h = o*tanh(c) = 2o*R3 - o  (U)

            pp[tt][pcol] = vh * wlin;              // deferred output partial
        }
        __syncthreads();

        // reduce 64 timesteps of output partials; one store per lane
        float s = blin;
        #pragma unroll
        for (int k = 0; k < HIDDEN; ++k) s += pp[lane][k];
        out[(size_t)(tb + lane) * BATCH + b] = s;
        __syncthreads();

        xv = xv_next;
    }
}

extern "C" void kernel_launch(void* const* d_in, const int* in_sizes, int n_in,
                              void* d_out, int out_size, void* d_ws, size_t ws_size,
                              hipStream_t stream) {
    const float* x     = (const float*)d_in[0];
    const float* W_ih  = (const float*)d_in[1];
    const float* W_hh  = (const float*)d_in[2];
    const float* b_ih  = (const float*)d_in[3];
    const float* b_hh  = (const float*)d_in[4];
    const float* W_lin = (const float*)d_in[5];
    const float* b_lin = (const float*)d_in[6];
    float* outp = (float*)d_out;

    hipLaunchKernelGGL(lstm_kernel, dim3(BATCH), dim3(64), 0, stream,
                       x, W_ih, W_hh, b_ih, b_hh, W_lin, b_lin, outp);
}

// Round 4
// 354.804 us; speedup vs baseline: 1.4422x; 1.0204x over previous
//
#include <hip/hip_runtime.h>

#define SEQ_LEN 2048
#define BATCH   512
#define HIDDEN  25

typedef int v2i __attribute__((ext_vector_type(2)));

__device__ __forceinline__ float fast_rcp(float v)  { return __builtin_amdgcn_rcpf(v); }
__device__ __forceinline__ float fast_exp2(float v) { return __builtin_amdgcn_exp2f(v); }

// Full lane<->lane^32 exchange, polarity-proof (one of r.x/r.y is always the
// unswapped value, so rx+ry-v == v[lane^32] regardless of HW polarity).
__device__ __forceinline__ float xswap32(float v) {
#if __has_builtin(__builtin_amdgcn_permlane32_swap)
    v2i r = __builtin_amdgcn_permlane32_swap(__float_as_int(v), __float_as_int(v), false, false);
    return (__int_as_float(r.x) + __int_as_float(r.y)) - v;
#else
    return __shfl_xor(v, 32);
#endif
}

// One wave per batch element.
//   L lane j  (0..24):  rows j      (i, sigmoid) and 50+j (g, tanh)  -> i*g local
//   U lane 32+j (0..24): rows 25+j  (f, sigmoid) and 75+j (o, sigmoid); owns c_j, h_j
// Single cross-lane move per step: i*g from L to U (permlane32_swap).
// Activation scales folded into weights; cell state kept as c' = -2log2e * c.
// Weights are PINNED into VGPRs via opaque inline asm so the compiler cannot
// re-materialize the loads inside the step loop (R2 showed VGPR_Count=40 ->
// loads were being replayed every step).
__global__ __launch_bounds__(64, 1) void lstm_kernel(
    const float* __restrict__ x,
    const float* __restrict__ W_ih,
    const float* __restrict__ W_hh,
    const float* __restrict__ b_ih,
    const float* __restrict__ b_hh,
    const float* __restrict__ W_lin,
    const float* __restrict__ b_lin,
    float* __restrict__ out)
{
    const int lane = threadIdx.x;
    const int b    = blockIdx.x;

    __shared__ float pp[64][29];   // deferred output partials; 29 coprime w/ 32 banks

    const bool U  = (lane >= 32);
    const int  j  = lane & 31;
    const int  jj = (j < HIDDEN) ? j : 0;          // clamp idle lanes to a harmless row
    const bool hv = (j < HIDDEN);

    const int r1 = U ? (HIDDEN + jj) : jj;                     // f : i  (sigmoid)
    const int r2 = U ? (3 * HIDDEN + jj) : (2 * HIDDEN + jj);  // o : g

    const float LOG2E = 1.4426950408889634f;
    const float s1 = -LOG2E;                       // sigmoid pre-scale
    const float s2 = U ? -LOG2E : (-2.0f * LOG2E); // o: sigmoid, g: tanh(=sig(2x) form)

    float Wr1[HIDDEN], Wr2[HIDDEN];
    #pragma unroll
    for (int k = 0; k < HIDDEN; ++k) {
        Wr1[k] = W_hh[r1 * HIDDEN + k] * s1;
        Wr2[k] = W_hh[r2 * HIDDEN + k] * s2;
    }
    float bias1 = (b_ih[r1] + b_hh[r1]) * s1;
    float bias2 = (b_ih[r2] + b_hh[r2]) * s2;
    float wi1   = W_ih[r1] * s1;
    float wi2   = W_ih[r2] * s2;

    // --- pin all loop-invariant operands into VGPRs (defeat load remat) ---
    #pragma unroll
    for (int k = 0; k < HIDDEN; ++k) {
        asm volatile("" : "+v"(Wr1[k]));
        asm volatile("" : "+v"(Wr2[k]));
    }
    asm volatile("" : "+v"(bias1), "+v"(bias2), "+v"(wi1), "+v"(wi2));

    const float wlin  = (U && hv) ? W_lin[jj] : 0.0f;
    const float blin  = b_lin[0];
    const int   pcol  = (U && hv) ? jj : 26;       // inactive lanes dump into unused col

    float cs = 0.0f;   // c' = -2log2e * c   (real on U lanes)
    float vh = 0.0f;   // h                  (real on U lanes)

    const float* xb = x + b;
    float xv = xb[(size_t)lane * BATCH];           // x[t=lane][b], staggered prefetch

    #pragma unroll 1
    for (int tb = 0; tb < SEQ_LEN; tb += 64) {
        float xv_next = 0.0f;
        if (tb + 64 < SEQ_LEN) xv_next = xb[(size_t)(tb + 64 + lane) * BATCH];

        #pragma unroll 4
        for (int tt = 0; tt < 64; ++tt) {
            // broadcast h(t-1) from U lanes into wave-uniform SGPRs
            float hs[HIDDEN];
            #pragma unroll
            for (int k = 0; k < HIDDEN; ++k)
                hs[k] = __int_as_float(__builtin_amdgcn_readlane(__float_as_int(vh), 32 + k));

            const float xt = __int_as_float(__builtin_amdgcn_readlane(__float_as_int(xv), tt));

            float a1 = fmaf(xt, wi1, bias1);
            float a2 = fmaf(xt, wi2, bias2);
            float b1 = 0.0f, b2 = 0.0f;
            #pragma unroll
            for (int k = 0; k < 24; k += 2) {      // 4 independent FMA chains
                a1 = fmaf(hs[k],     Wr1[k],     a1);
                b1 = fmaf(hs[k + 1], Wr1[k + 1], b1);
                a2 = fmaf(hs[k],     Wr2[k],     a2);
                b2 = fmaf(hs[k + 1], Wr2[k + 1], b2);
            }
            a1 = fmaf(hs[24], Wr1[24], a1) + b1;
            a2 = fmaf(hs[24], Wr2[24], a2) + b2;

            const float R1 = fast_rcp(1.0f + fast_exp2(a1));   // i (L) / f (U)
            const float R2 = fast_rcp(1.0f + fast_exp2(a2));   // sig(2zg) (L) / o (U)

            // L: igs = i * g * (-2log2e), where g = 2*R2 - 1
            const float Gp  = fmaf(R2, -4.0f * LOG2E, 2.0f * LOG2E);
            const float igs = R1 * Gp;
            const float igx = xswap32(igs);        // U lanes receive L's igs

            cs = fmaf(R1, cs, igx);                // c' = f*c' + (-2log2e)*i*g  (U)
            const float R3 = fast_rcp(1.0f + fast_exp2(cs));   // sig(2c) -> tanh(c)=2R3-1
            const float o2 = R2 + R2;              // 2o (off critical path)
            vh = fmaf(o2, R3, -R2);                // h = o*tanh(c) = 2o*R3 - o  (U)

            pp[tt][pcol] = vh * wlin;              // deferred output partial
        }
        __syncthreads();

        // reduce 64 timesteps of output partials; one store per lane
        float s = blin;
        #pragma unroll
        for (int k = 0; k < HIDDEN; ++k) s += pp[lane][k];
        out[(size_t)(tb + lane) * BATCH + b] = s;
        __syncthreads();

        xv = xv_next;
    }
}

extern "C" void kernel_launch(void* const* d_in, const int* in_sizes, int n_in,
                              void* d_out, int out_size, void* d_ws, size_t ws_size,
                              hipStream_t stream) {
    const float* x     = (const float*)d_in[0];
    const float* W_ih  = (const float*)d_in[1];
    const float* W_hh  = (const float*)d_in[2];
    const float* b_ih  = (const float*)d_in[3];
    const float* b_hh  = (const float*)d_in[4];
    const float* W_lin = (const float*)d_in[5];
    const float* b_lin = (const float*)d_in[6];
    float* outp = (float*)d_out;

    hipLaunchKernelGGL(lstm_kernel, dim3(BATCH), dim3(64), 0, stream,
                       x, W_ih, W_hh, b_ih, b_hh, W_lin, b_lin, outp);
}

// Round 5
// 354.515 us; speedup vs baseline: 1.4433x; 1.0008x over previous
//
#include <hip/hip_runtime.h>

#define SEQ_LEN 2048
#define BATCH   512
#define HIDDEN  25

typedef int v2i __attribute__((ext_vector_type(2)));

__device__ __forceinline__ float fast_rcp(float v)  { return __builtin_amdgcn_rcpf(v); }
__device__ __forceinline__ float fast_exp2(float v) { return __builtin_amdgcn_exp2f(v); }

// Full lane<->lane^32 exchange, polarity-proof (one of r.x/r.y is always the
// unswapped value, so rx+ry-v == v[lane^32] regardless of HW polarity).
__device__ __forceinline__ float xswap32(float v) {
#if __has_builtin(__builtin_amdgcn_permlane32_swap)
    v2i r = __builtin_amdgcn_permlane32_swap(__float_as_int(v), __float_as_int(v), false, false);
    return (__int_as_float(r.x) + __int_as_float(r.y)) - v;
#else
    return __shfl_xor(v, 32);
#endif
}

// One wave per batch element.
//   L lane j  (0..24):  rows j      (i, sigmoid) and 50+j (g, tanh)  -> i*g local
//   U lane 32+j (0..24): rows 25+j  (f, sigmoid) and 75+j (o, sigmoid); owns c_j, h_j
// Single cross-lane move per step: i*g from L to U (permlane32_swap).
// Activation scales folded into weights; cell state kept as c' = -2log2e * c.
// amdgpu_waves_per_eu(1,1): occupancy is 0.5 waves/SIMD by grid construction
// (512 waves / 1024 SIMDs), so cap the compiler's occupancy target at 1 to
// give the allocator the full 512-VGPR budget -> weights stay register-
// resident instead of being spilled/reloaded every step (R2/R3: VGPR=40).
__global__ __launch_bounds__(64)
__attribute__((amdgpu_waves_per_eu(1, 1)))
void lstm_kernel(
    const float* __restrict__ x,
    const float* __restrict__ W_ih,
    const float* __restrict__ W_hh,
    const float* __restrict__ b_ih,
    const float* __restrict__ b_hh,
    const float* __restrict__ W_lin,
    const float* __restrict__ b_lin,
    float* __restrict__ out)
{
    const int lane = threadIdx.x;
    const int b    = blockIdx.x;

    __shared__ float pp[64][29];   // deferred output partials; 29 coprime w/ 32 banks

    const bool U  = (lane >= 32);
    const int  j  = lane & 31;
    const int  jj = (j < HIDDEN) ? j : 0;          // clamp idle lanes to a harmless row
    const bool hv = (j < HIDDEN);

    const int r1 = U ? (HIDDEN + jj) : jj;                     // f : i  (sigmoid)
    const int r2 = U ? (3 * HIDDEN + jj) : (2 * HIDDEN + jj);  // o : g

    const float LOG2E = 1.4426950408889634f;
    const float s1 = -LOG2E;                       // sigmoid pre-scale
    const float s2 = U ? -LOG2E : (-2.0f * LOG2E); // o: sigmoid, g: tanh(=sig(2x) form)

    float Wr1[HIDDEN], Wr2[HIDDEN];
    #pragma unroll
    for (int k = 0; k < HIDDEN; ++k) {
        Wr1[k] = W_hh[r1 * HIDDEN + k] * s1;
        Wr2[k] = W_hh[r2 * HIDDEN + k] * s2;
    }
    float bias1 = (b_ih[r1] + b_hh[r1]) * s1;
    float bias2 = (b_ih[r2] + b_hh[r2]) * s2;
    float wi1   = W_ih[r1] * s1;
    float wi2   = W_ih[r2] * s2;

    // --- pin all loop-invariant operands into VGPRs (defeat load remat) ---
    #pragma unroll
    for (int k = 0; k < HIDDEN; ++k) {
        asm volatile("" : "+v"(Wr1[k]));
        asm volatile("" : "+v"(Wr2[k]));
    }
    asm volatile("" : "+v"(bias1), "+v"(bias2), "+v"(wi1), "+v"(wi2));

    const float wlin  = (U && hv) ? W_lin[jj] : 0.0f;
    const float blin  = b_lin[0];
    const int   pcol  = (U && hv) ? jj : 26;       // inactive lanes dump into unused col

    float cs = 0.0f;   // c' = -2log2e * c   (real on U lanes)
    float vh = 0.0f;   // h                  (real on U lanes)

    const float* xb = x + b;
    float xv = xb[(size_t)lane * BATCH];           // x[t=lane][b], staggered prefetch

    #pragma unroll 1
    for (int tb = 0; tb < SEQ_LEN; tb += 64) {
        float xv_next = 0.0f;
        if (tb + 64 < SEQ_LEN) xv_next = xb[(size_t)(tb + 64 + lane) * BATCH];

        #pragma unroll 4
        for (int tt = 0; tt < 64; ++tt) {
            // broadcast h(t-1) from U lanes into wave-uniform SGPRs
            float hs[HIDDEN];
            #pragma unroll
            for (int k = 0; k < HIDDEN; ++k)
                hs[k] = __int_as_float(__builtin_amdgcn_readlane(__float_as_int(vh), 32 + k));

            const float xt = __int_as_float(__builtin_amdgcn_readlane(__float_as_int(xv), tt));

            float a1 = fmaf(xt, wi1, bias1);
            float a2 = fmaf(xt, wi2, bias2);
            float b1 = 0.0f, b2 = 0.0f;
            #pragma unroll
            for (int k = 0; k < 24; k += 2) {      // 4 independent FMA chains
                a1 = fmaf(hs[k],     Wr1[k],     a1);
                b1 = fmaf(hs[k + 1], Wr1[k + 1], b1);
                a2 = fmaf(hs[k],     Wr2[k],     a2);
                b2 = fmaf(hs[k + 1], Wr2[k + 1], b2);
            }
            a1 = fmaf(hs[24], Wr1[24], a1) + b1;
            a2 = fmaf(hs[24], Wr2[24], a2) + b2;

            const float R1 = fast_rcp(1.0f + fast_exp2(a1));   // i (L) / f (U)
            const float R2 = fast_rcp(1.0f + fast_exp2(a2));   // sig(2zg) (L) / o (U)

            // L: igs = i * g * (-2log2e), where g = 2*R2 - 1
            const float Gp  = fmaf(R2, -4.0f * LOG2E, 2.0f * LOG2E);
            const float igs = R1 * Gp;
            const float igx = xswap32(igs);        // U lanes receive L's igs

            cs = fmaf(R1, cs, igx);                // c' = f*c' + (-2log2e)*i*g  (U)
            const float R3 = fast_rcp(1.0f + fast_exp2(cs));   // sig(2c) -> tanh(c)=2R3-1
            const float o2 = R2 + R2;              // 2o (off critical path)
            vh = fmaf(o2, R3, -R2);                // h = o*tanh(c) = 2o*R3 - o  (U)

            pp[tt][pcol] = vh * wlin;              // deferred output partial
        }
        __syncthreads();

        // reduce 64 timesteps of output partials; one store per lane
        float s = blin;
        #pragma unroll
        for (int k = 0; k < HIDDEN; ++k) s += pp[lane][k];
        out[(size_t)(tb + lane) * BATCH + b] = s;
        __syncthreads();

        xv = xv_next;
    }
}

extern "C" void kernel_launch(void* const* d_in, const int* in_sizes, int n_in,
                              void* d_out, int out_size, void* d_ws, size_t ws_size,
                              hipStream_t stream) {
    const float* x     = (const float*)d_in[0];
    const float* W_ih  = (const float*)d_in[1];
    const float* W_hh  = (const float*)d_in[2];
    const float* b_ih  = (const float*)d_in[3];
    const float* b_hh  = (const float*)d_in[4];
    const float* W_lin = (const float*)d_in[5];
    const float* b_lin = (const float*)d_in[6];
    float* outp = (float*)d_out;

    hipLaunchKernelGGL(lstm_kernel, dim3(BATCH), dim3(64), 0, stream,
                       x, W_ih, W_hh, b_ih, b_hh, W_lin, b_lin, outp);
}

// Round 6
// 326.796 us; speedup vs baseline: 1.5658x; 1.0848x over previous
//
#include <hip/hip_runtime.h>

#define SEQ_LEN 2048
#define BATCH   512
#define HIDDEN  25

typedef int v2i __attribute__((ext_vector_type(2)));
typedef _Float16 h2_t __attribute__((ext_vector_type(2)));

__device__ __forceinline__ float fast_rcp(float v)  { return __builtin_amdgcn_rcpf(v); }
__device__ __forceinline__ float fast_exp2(float v) { return __builtin_amdgcn_exp2f(v); }

// D = a.lo*b.lo + a.hi*b.hi + c, f16 multiply / f32 accumulate
__device__ __forceinline__ float fdot2i(int a, int b, float c) {
#if __has_builtin(__builtin_amdgcn_fdot2)
    return __builtin_amdgcn_fdot2(__builtin_bit_cast(h2_t, a), __builtin_bit_cast(h2_t, b), c, false);
#else
    float d;
    asm("v_dot2_f32_f16 %0, %1, %2, %3" : "=v"(d) : "v"(a), "v"(b), "v"(c));
    return d;
#endif
}

// Full lane<->lane^32 exchange, polarity-proof.
__device__ __forceinline__ float xswap32(float v) {
#if __has_builtin(__builtin_amdgcn_permlane32_swap)
    v2i r = __builtin_amdgcn_permlane32_swap(__float_as_int(v), __float_as_int(v), false, false);
    return (__int_as_float(r.x) + __int_as_float(r.y)) - v;
#else
    return __shfl_xor(v, 32);
#endif
}

// One wave per batch element.
//   L lane j  (0..24):  rows j (i, sigmoid) and 50+j (g, tanh)  -> i*g local
//   U lane 32+j (0..24): rows 25+j (f) and 75+j (o); owns c_j, h_j
// h crosses as PACKED f16 pairs: U lane packs {h_j, h_{j^1}} via DPP quad-perm
// + cvt_pkrtz; 13 readlanes (even U lanes) broadcast all 25 h values (k=25
// slot is weight-padded to zero). Dot products use v_dot2_f32_f16 (f32 acc).
__global__ __launch_bounds__(64)
__attribute__((amdgpu_waves_per_eu(1, 1)))
void lstm_kernel(
    const float* __restrict__ x,
    const float* __restrict__ W_ih,
    const float* __restrict__ W_hh,
    const float* __restrict__ b_ih,
    const float* __restrict__ b_hh,
    const float* __restrict__ W_lin,
    const float* __restrict__ b_lin,
    float* __restrict__ out)
{
    const int lane = threadIdx.x;
    const int b    = blockIdx.x;

    __shared__ float pp[64][29];   // deferred output partials; 29 coprime w/ 32 banks

    const bool U  = (lane >= 32);
    const int  j  = lane & 31;
    const int  jj = (j < HIDDEN) ? j : 0;          // clamp idle lanes to a harmless row
    const bool hv = (j < HIDDEN);

    const int r1 = U ? (HIDDEN + jj) : jj;                     // f : i  (sigmoid)
    const int r2 = U ? (3 * HIDDEN + jj) : (2 * HIDDEN + jj);  // o : g

    const float LOG2E = 1.4426950408889634f;
    const float s1 = -LOG2E;                       // sigmoid pre-scale
    const float s2 = U ? -LOG2E : (-2.0f * LOG2E); // o: sigmoid, g: tanh(=sig(2x) form)

    // fold scales into weights, pad k=25 with 0, pack to f16 pairs
    float w1[26], w2[26];
    #pragma unroll
    for (int k = 0; k < HIDDEN; ++k) {
        w1[k] = W_hh[r1 * HIDDEN + k] * s1;
        w2[k] = W_hh[r2 * HIDDEN + k] * s2;
    }
    w1[25] = 0.0f; w2[25] = 0.0f;
    int W1p[13], W2p[13];
    #pragma unroll
    for (int m = 0; m < 13; ++m) {
        W1p[m] = __builtin_bit_cast(int, __builtin_amdgcn_cvt_pkrtz(w1[2*m], w1[2*m+1]));
        W2p[m] = __builtin_bit_cast(int, __builtin_amdgcn_cvt_pkrtz(w2[2*m], w2[2*m+1]));
    }
    float bias1 = (b_ih[r1] + b_hh[r1]) * s1;
    float bias2 = (b_ih[r2] + b_hh[r2]) * s2;
    float wi1   = W_ih[r1] * s1;
    float wi2   = W_ih[r2] * s2;

    // pin loop-invariants into VGPRs (defeat remat/spill)
    #pragma unroll
    for (int m = 0; m < 13; ++m) {
        asm volatile("" : "+v"(W1p[m]));
        asm volatile("" : "+v"(W2p[m]));
    }
    asm volatile("" : "+v"(bias1), "+v"(bias2), "+v"(wi1), "+v"(wi2));

    const float wlin  = (U && hv) ? W_lin[jj] : 0.0f;
    const float blin  = b_lin[0];
    const int   pcol  = (U && hv) ? jj : 26;       // inactive lanes dump into unused col

    float cs = 0.0f;   // c' = -2log2e * c   (real on U lanes)
    float vh = 0.0f;   // h                  (real on U lanes)

    const float* xb = x + b;
    float xv = xb[(size_t)lane * BATCH];           // x[t=lane][b], staggered prefetch

    #pragma unroll 1
    for (int tb = 0; tb < SEQ_LEN; tb += 64) {
        float xv_next = 0.0f;
        if (tb + 64 < SEQ_LEN) xv_next = xb[(size_t)(tb + 64 + lane) * BATCH];

        #pragma unroll 4
        for (int tt = 0; tt < 64; ++tt) {
            // pack {h_j, h_{j^1}} as f16x2 (valid on even U lanes)
            const int vhn = __builtin_amdgcn_mov_dpp(__float_as_int(vh), 0xB1, 0xF, 0xF, true);
            const int hpk = __builtin_bit_cast(int,
                __builtin_amdgcn_cvt_pkrtz(vh, __int_as_float(vhn)));

            // broadcast 25 h values as 13 packed words from even U lanes
            int hw[13];
            #pragma unroll
            for (int m = 0; m < 13; ++m)
                hw[m] = __builtin_amdgcn_readlane(hpk, 32 + 2 * m);

            const float xt = __int_as_float(__builtin_amdgcn_readlane(__float_as_int(xv), tt));

            float a1 = fmaf(xt, wi1, bias1);
            float a2 = fmaf(xt, wi2, bias2);
            float b1 = 0.0f, b2 = 0.0f;
            #pragma unroll
            for (int m = 0; m < 12; m += 2) {      // 4 independent dot2 chains
                a1 = fdot2i(W1p[m],     hw[m],     a1);
                b1 = fdot2i(W1p[m + 1], hw[m + 1], b1);
                a2 = fdot2i(W2p[m],     hw[m],     a2);
                b2 = fdot2i(W2p[m + 1], hw[m + 1], b2);
            }
            a1 = fdot2i(W1p[12], hw[12], a1) + b1;
            a2 = fdot2i(W2p[12], hw[12], a2) + b2;

            const float R1 = fast_rcp(1.0f + fast_exp2(a1));   // i (L) / f (U)
            const float R2 = fast_rcp(1.0f + fast_exp2(a2));   // sig(2zg) (L) / o (U)

            // L: igs = i * g * (-2log2e), where g = 2*R2 - 1
            const float Gp  = fmaf(R2, -4.0f * LOG2E, 2.0f * LOG2E);
            const float igs = R1 * Gp;
            const float igx = xswap32(igs);        // U lanes receive L's igs

            cs = fmaf(R1, cs, igx);                // c' = f*c' + (-2log2e)*i*g  (U)
            const float R3 = fast_rcp(1.0f + fast_exp2(cs));   // sig(2c) -> tanh(c)=2R3-1
            const float o2 = R2 + R2;              // 2o (off critical path)
            vh = fmaf(o2, R3, -R2);                // h = o*tanh(c) = 2o*R3 - o  (U)

            pp[tt][pcol] = vh * wlin;              // deferred output partial
        }
        __syncthreads();

        // reduce 64 timesteps of output partials; one store per lane
        float s = blin;
        #pragma unroll
        for (int k = 0; k < HIDDEN; ++k) s += pp[lane][k];
        out[(size_t)(tb + lane) * BATCH + b] = s;
        __syncthreads();

        xv = xv_next;
    }
}

extern "C" void kernel_launch(void* const* d_in, const int* in_sizes, int n_in,
                              void* d_out, int out_size, void* d_ws, size_t ws_size,
                              hipStream_t stream) {
    const float* x     = (const float*)d_in[0];
    const float* W_ih  = (const float*)d_in[1];
    const float* W_hh  = (const float*)d_in[2];
    const float* b_ih  = (const float*)d_in[3];
    const float* b_hh  = (const float*)d_in[4];
    const float* W_lin = (const float*)d_in[5];
    const float* b_lin = (const float*)d_in[6];
    float* outp = (float*)d_out;

    hipLaunchKernelGGL(lstm_kernel, dim3(BATCH), dim3(64), 0, stream,
                       x, W_ih, W_hh, b_ih, b_hh, W_lin, b_lin, outp);
}